// Round 1
// baseline (1666.262 us; speedup 1.0000x reference)
//
#include <hip/hip_runtime.h>

// GCN_88734024335852 — 2-layer GCN on MI355X
//
// Math refactor: with dinv[i] = rsqrt(deg_in[i]+1),
//   layer out[c] = dinv[c] * ( g[c] + sum_{e: col[e]==c} g[row[e]] ) + b
// where g[i] = (h[i] @ W) * dinv[i]   (self-loop term absorbed).
//
// ws layout (floats): degf[n] dinv[n] xe[n] g[16n] acc1[16n] g2[n] acc2[n]
//   total 37n floats = 14.8 MB for n=100000.

#define D_FEAT 128
#define HIDDEN 16

__global__ __launch_bounds__(256) void k_init(float* degf, float* xe, float* acc1,
                                              float* acc2, int n) {
    int t = blockIdx.x * 256 + threadIdx.x;
    if (t < n * HIDDEN) acc1[t] = 0.f;
    if (t < n) {
        degf[t] = 1.0f;   // self-loop
        xe[t]   = 0.f;
        acc2[t] = 0.f;
    }
}

__global__ __launch_bounds__(256) void k_edge_prep(const int* __restrict__ row,
                                                   const int* __restrict__ col,
                                                   const float* __restrict__ ea,
                                                   float* degf, float* xe, int ne) {
    int e = blockIdx.x * 256 + threadIdx.x;
    if (e >= ne) return;
    unsafeAtomicAdd(&degf[col[e]], 1.0f);
    unsafeAtomicAdd(&xe[row[e]], ea[e]);
}

__global__ __launch_bounds__(256) void k_dinv(const float* degf, float* dinv, int n) {
    int i = blockIdx.x * 256 + threadIdx.x;
    if (i < n) dinv[i] = rsqrtf(degf[i]);
}

// g[i][j] = (sum_k x[i][k]*W1[k][j] + xe[i]*W1[128][j]) * dinv[i]
// Tile: 64 nodes/block, 256 threads. x staged in LDS (coalesced float4).
__global__ __launch_bounds__(256) void k_gemm1(const float* __restrict__ x,
                                               const float* __restrict__ xe,
                                               const float* __restrict__ dinv,
                                               const float* __restrict__ W1,
                                               float* __restrict__ g, int n) {
    __shared__ float Ws[129 * 16];
    __shared__ float xs[64 * 132];   // row stride 132 (16B aligned, breaks bank stride)
    int tid = threadIdx.x;
    for (int idx = tid; idx < 129 * 16; idx += 256) Ws[idx] = W1[idx];
    int n0 = blockIdx.x * 64;
    const float4* x4 = (const float4*)x;
    for (int idx = tid; idx < 64 * 32; idx += 256) {
        int r = idx >> 5, c = idx & 31;
        float4 v = (n0 + r < n) ? x4[(size_t)(n0 + r) * 32 + c]
                                : make_float4(0.f, 0.f, 0.f, 0.f);
        *(float4*)&xs[r * 132 + c * 4] = v;
    }
    if (tid < 64) {
        int r = tid;
        xs[r * 132 + 128] = (n0 + r < n) ? xe[n0 + r] : 0.f;
    }
    __syncthreads();
    int j  = tid & 15;
    int nb = tid >> 4;                 // 0..15
    for (int rep = 0; rep < 4; ++rep) {
        int nl = nb + (rep << 4);      // 0..63
        int node = n0 + nl;
        const float* xrow = &xs[nl * 132];
        float acc = 0.f;
        #pragma unroll
        for (int k = 0; k < 128; k += 4) {
            float4 xv = *(const float4*)&xrow[k];
            acc += xv.x * Ws[(k + 0) * 16 + j];
            acc += xv.y * Ws[(k + 1) * 16 + j];
            acc += xv.z * Ws[(k + 2) * 16 + j];
            acc += xv.w * Ws[(k + 3) * 16 + j];
        }
        acc += xrow[128] * Ws[128 * 16 + j];
        if (node < n) g[node * 16 + j] = acc * dinv[node];
    }
}

// acc1[col[e]][j] += g[row[e]][j] ; one thread per (edge, j)
__global__ __launch_bounds__(256) void k_agg16(const int* __restrict__ row,
                                               const int* __restrict__ col,
                                               const float* __restrict__ g,
                                               float* __restrict__ acc1,
                                               long long ne16) {
    long long t = (long long)blockIdx.x * 256 + threadIdx.x;
    if (t >= ne16) return;
    int e = (int)(t >> 4);
    int j = (int)(t & 15);
    int r = row[e], c = col[e];
    unsafeAtomicAdd(&acc1[c * 16 + j], g[r * 16 + j]);
}

// h1 = relu(dinv*(g+acc1)+b1); z = h1@W2; g2 = z*dinv   (16 lanes per node)
__global__ __launch_bounds__(256) void k_layer1_post(const float* __restrict__ dinv,
                                                     const float* __restrict__ g,
                                                     const float* __restrict__ acc1,
                                                     const float* __restrict__ b1,
                                                     const float* __restrict__ W2,
                                                     float* __restrict__ g2, int n) {
    int t = blockIdx.x * 256 + threadIdx.x;
    int i = t >> 4, j = t & 15;
    if (i >= n) return;
    float di = dinv[i];
    float v = di * (g[i * 16 + j] + acc1[i * 16 + j]) + b1[j];
    v = fmaxf(v, 0.f);
    float p = v * W2[j];
    p += __shfl_down(p, 8, 16);
    p += __shfl_down(p, 4, 16);
    p += __shfl_down(p, 2, 16);
    p += __shfl_down(p, 1, 16);
    if (j == 0) g2[i] = p * di;
}

__global__ __launch_bounds__(256) void k_agg1(const int* __restrict__ row,
                                              const int* __restrict__ col,
                                              const float* __restrict__ g2,
                                              float* __restrict__ acc2, int ne) {
    int e = blockIdx.x * 256 + threadIdx.x;
    if (e >= ne) return;
    unsafeAtomicAdd(&acc2[col[e]], g2[row[e]]);
}

__global__ __launch_bounds__(256) void k_out(const float* __restrict__ dinv,
                                             const float* __restrict__ g2,
                                             const float* __restrict__ acc2,
                                             const float* __restrict__ b2,
                                             float* __restrict__ out, int n) {
    int i = blockIdx.x * 256 + threadIdx.x;
    if (i < n) out[i] = dinv[i] * (g2[i] + acc2[i]) + b2[0];
}

extern "C" void kernel_launch(void* const* d_in, const int* in_sizes, int n_in,
                              void* d_out, int out_size, void* d_ws, size_t ws_size,
                              hipStream_t stream) {
    const float* x   = (const float*)d_in[0];
    const float* ea  = (const float*)d_in[1];
    const int*   row = (const int*)d_in[2];
    const int*   col = (const int*)d_in[3];
    const float* W1  = (const float*)d_in[4];
    const float* b1  = (const float*)d_in[5];
    const float* W2  = (const float*)d_in[6];
    const float* b2  = (const float*)d_in[7];
    float* out = (float*)d_out;

    int n  = in_sizes[0] / D_FEAT;   // 100000
    int ne = in_sizes[2];            // 6400000

    float* ws   = (float*)d_ws;
    float* degf = ws;                // n
    float* dinv = ws + (size_t)n;    // n
    float* xe   = ws + (size_t)2 * n;  // n
    float* g    = ws + (size_t)3 * n;  // 16n
    float* acc1 = ws + (size_t)19 * n; // 16n
    float* g2   = ws + (size_t)35 * n; // n
    float* acc2 = ws + (size_t)36 * n; // n

    dim3 blk(256);
    int g_init  = (n * HIDDEN + 255) / 256;
    int g_edge  = (ne + 255) / 256;
    int g_node  = (n + 255) / 256;
    int g_gemm  = (n + 63) / 64;
    long long ne16 = (long long)ne * HIDDEN;
    int g_agg16 = (int)((ne16 + 255) / 256);
    int g_n16   = (n * HIDDEN + 255) / 256;

    k_init<<<g_init, blk, 0, stream>>>(degf, xe, acc1, acc2, n);
    k_edge_prep<<<g_edge, blk, 0, stream>>>(row, col, ea, degf, xe, ne);
    k_dinv<<<g_node, blk, 0, stream>>>(degf, dinv, n);
    k_gemm1<<<g_gemm, blk, 0, stream>>>(x, xe, dinv, W1, g, n);
    k_agg16<<<g_agg16, blk, 0, stream>>>(row, col, g, acc1, ne16);
    k_layer1_post<<<g_n16, blk, 0, stream>>>(dinv, g, acc1, b1, W2, g2, n);
    k_agg1<<<g_edge, blk, 0, stream>>>(row, col, g2, acc2, ne);
    k_out<<<g_node, blk, 0, stream>>>(dinv, g2, acc2, b2, out, n);
}

// Round 2
// 1145.958 us; speedup vs baseline: 1.4540x; 1.4540x over previous
//
#include <hip/hip_runtime.h>

// GCN_88734024335852 — 2-layer GCN on MI355X
//
// Math refactor: with dinv[i] = rsqrt(deg_in[i]+1),
//   layer out[c] = dinv[c] * ( g[c] + sum_{e: col[e]==c} g[row[e]] ) + b
// where g[i] = (h[i] @ W) * dinv[i]   (self-loop term absorbed).
//
// R2: edge_row is SORTED -> xe segment-sum via wave segmented scan
//     (64-way same-address atomic serialization was 880us in R1).
//
// ws layout (floats): degf[n] dinv[n] xe[n] g[16n] acc1[16n] g2[n] acc2[n]

#define D_FEAT 128
#define HIDDEN 16

__global__ __launch_bounds__(256) void k_init(float* degf, float* xe, float* acc1,
                                              float* acc2, int n) {
    int t = blockIdx.x * 256 + threadIdx.x;
    if (t < n * HIDDEN) acc1[t] = 0.f;
    if (t < n) {
        degf[t] = 1.0f;   // self-loop
        xe[t]   = 0.f;
        acc2[t] = 0.f;
    }
}

// degf[col[e]] += 1 (cols random -> plain atomic).
// xe[row[e]] += ea[e] with rows sorted -> wave segmented scan, tail-lane atomic.
__global__ __launch_bounds__(256) void k_edge_prep(const int* __restrict__ row,
                                                   const int* __restrict__ col,
                                                   const float* __restrict__ ea,
                                                   float* degf, float* xe, int ne) {
    int e = blockIdx.x * 256 + threadIdx.x;
    int lane = threadIdx.x & 63;
    bool valid = e < ne;
    int r = valid ? row[e] : -1;
    float a = valid ? ea[e] : 0.f;
    if (valid) unsafeAtomicAdd(&degf[col[e]], 1.0f);
    // inclusive segmented scan over the wave (segments = runs of equal r)
    #pragma unroll
    for (int d = 1; d < 64; d <<= 1) {
        float up = __shfl_up(a, d);
        int  rup = __shfl_up(r, d);
        if (lane >= d && rup == r) a += up;
    }
    int rdn = __shfl_down(r, 1);
    bool tail = (lane == 63) || (rdn != r);
    if (valid && tail) unsafeAtomicAdd(&xe[r], a);
}

__global__ __launch_bounds__(256) void k_dinv(const float* degf, float* dinv, int n) {
    int i = blockIdx.x * 256 + threadIdx.x;
    if (i < n) dinv[i] = rsqrtf(degf[i]);
}

// g[i][j] = (sum_k x[i][k]*W1[k][j] + xe[i]*W1[128][j]) * dinv[i]
__global__ __launch_bounds__(256) void k_gemm1(const float* __restrict__ x,
                                               const float* __restrict__ xe,
                                               const float* __restrict__ dinv,
                                               const float* __restrict__ W1,
                                               float* __restrict__ g, int n) {
    __shared__ float Ws[129 * 16];
    __shared__ float xs[64 * 132];
    int tid = threadIdx.x;
    for (int idx = tid; idx < 129 * 16; idx += 256) Ws[idx] = W1[idx];
    int n0 = blockIdx.x * 64;
    const float4* x4 = (const float4*)x;
    for (int idx = tid; idx < 64 * 32; idx += 256) {
        int r = idx >> 5, c = idx & 31;
        float4 v = (n0 + r < n) ? x4[(size_t)(n0 + r) * 32 + c]
                                : make_float4(0.f, 0.f, 0.f, 0.f);
        *(float4*)&xs[r * 132 + c * 4] = v;
    }
    if (tid < 64) {
        int r = tid;
        xs[r * 132 + 128] = (n0 + r < n) ? xe[n0 + r] : 0.f;
    }
    __syncthreads();
    int j  = tid & 15;
    int nb = tid >> 4;
    for (int rep = 0; rep < 4; ++rep) {
        int nl = nb + (rep << 4);
        int node = n0 + nl;
        const float* xrow = &xs[nl * 132];
        float acc = 0.f;
        #pragma unroll
        for (int k = 0; k < 128; k += 4) {
            float4 xv = *(const float4*)&xrow[k];
            acc += xv.x * Ws[(k + 0) * 16 + j];
            acc += xv.y * Ws[(k + 1) * 16 + j];
            acc += xv.z * Ws[(k + 2) * 16 + j];
            acc += xv.w * Ws[(k + 3) * 16 + j];
        }
        acc += xrow[128] * Ws[128 * 16 + j];
        if (node < n) g[node * 16 + j] = acc * dinv[node];
    }
}

// acc1[col[e]][j] += g[row[e]][j] ; one thread per (edge, j)
__global__ __launch_bounds__(256) void k_agg16(const int* __restrict__ row,
                                               const int* __restrict__ col,
                                               const float* __restrict__ g,
                                               float* __restrict__ acc1,
                                               long long ne16) {
    long long t = (long long)blockIdx.x * 256 + threadIdx.x;
    if (t >= ne16) return;
    int e = (int)(t >> 4);
    int j = (int)(t & 15);
    int r = row[e], c = col[e];
    unsafeAtomicAdd(&acc1[c * 16 + j], g[r * 16 + j]);
}

// h1 = relu(dinv*(g+acc1)+b1); z = h1@W2; g2 = z*dinv   (16 lanes per node)
__global__ __launch_bounds__(256) void k_layer1_post(const float* __restrict__ dinv,
                                                     const float* __restrict__ g,
                                                     const float* __restrict__ acc1,
                                                     const float* __restrict__ b1,
                                                     const float* __restrict__ W2,
                                                     float* __restrict__ g2, int n) {
    int t = blockIdx.x * 256 + threadIdx.x;
    int i = t >> 4, j = t & 15;
    if (i >= n) return;
    float di = dinv[i];
    float v = di * (g[i * 16 + j] + acc1[i * 16 + j]) + b1[j];
    v = fmaxf(v, 0.f);
    float p = v * W2[j];
    p += __shfl_down(p, 8, 16);
    p += __shfl_down(p, 4, 16);
    p += __shfl_down(p, 2, 16);
    p += __shfl_down(p, 1, 16);
    if (j == 0) g2[i] = p * di;
}

__global__ __launch_bounds__(256) void k_agg1(const int* __restrict__ row,
                                              const int* __restrict__ col,
                                              const float* __restrict__ g2,
                                              float* __restrict__ acc2, int ne) {
    int e = blockIdx.x * 256 + threadIdx.x;
    if (e >= ne) return;
    unsafeAtomicAdd(&acc2[col[e]], g2[row[e]]);
}

__global__ __launch_bounds__(256) void k_out(const float* __restrict__ dinv,
                                             const float* __restrict__ g2,
                                             const float* __restrict__ acc2,
                                             const float* __restrict__ b2,
                                             float* __restrict__ out, int n) {
    int i = blockIdx.x * 256 + threadIdx.x;
    if (i < n) out[i] = dinv[i] * (g2[i] + acc2[i]) + b2[0];
}

extern "C" void kernel_launch(void* const* d_in, const int* in_sizes, int n_in,
                              void* d_out, int out_size, void* d_ws, size_t ws_size,
                              hipStream_t stream) {
    const float* x   = (const float*)d_in[0];
    const float* ea  = (const float*)d_in[1];
    const int*   row = (const int*)d_in[2];
    const int*   col = (const int*)d_in[3];
    const float* W1  = (const float*)d_in[4];
    const float* b1  = (const float*)d_in[5];
    const float* W2  = (const float*)d_in[6];
    const float* b2  = (const float*)d_in[7];
    float* out = (float*)d_out;

    int n  = in_sizes[0] / D_FEAT;   // 100000
    int ne = in_sizes[2];            // 6400000

    float* ws   = (float*)d_ws;
    float* degf = ws;                  // n
    float* dinv = ws + (size_t)n;      // n
    float* xe   = ws + (size_t)2 * n;  // n
    float* g    = ws + (size_t)3 * n;  // 16n
    float* acc1 = ws + (size_t)19 * n; // 16n
    float* g2   = ws + (size_t)35 * n; // n
    float* acc2 = ws + (size_t)36 * n; // n

    dim3 blk(256);
    int g_init  = (n * HIDDEN + 255) / 256;
    int g_edge  = (ne + 255) / 256;
    int g_node  = (n + 255) / 256;
    int g_gemm  = (n + 63) / 64;
    long long ne16 = (long long)ne * HIDDEN;
    int g_agg16 = (int)((ne16 + 255) / 256);
    int g_n16   = (n * HIDDEN + 255) / 256;

    k_init<<<g_init, blk, 0, stream>>>(degf, xe, acc1, acc2, n);
    k_edge_prep<<<g_edge, blk, 0, stream>>>(row, col, ea, degf, xe, ne);
    k_dinv<<<g_node, blk, 0, stream>>>(degf, dinv, n);
    k_gemm1<<<g_gemm, blk, 0, stream>>>(x, xe, dinv, W1, g, n);
    k_agg16<<<g_agg16, blk, 0, stream>>>(row, col, g, acc1, ne16);
    k_layer1_post<<<g_n16, blk, 0, stream>>>(dinv, g, acc1, b1, W2, g2, n);
    k_agg1<<<g_edge, blk, 0, stream>>>(row, col, g2, acc2, ne);
    k_out<<<g_node, blk, 0, stream>>>(dinv, g2, acc2, b2, out, n);
}

// Round 3
// 1019.611 us; speedup vs baseline: 1.6342x; 1.1239x over previous
//
#include <hip/hip_runtime.h>

// GCN_88734024335852 — 2-layer GCN on MI355X
//
// R3: scattered global fp32 atomics cost ~32B fabric traffic each (R2 rocprof:
// WRITE_SIZE 203MB = 6.4M x 32B, ~23G atomics/s ceiling). Restructure:
// counting-sort edges by col into 391 buckets of 256 nodes (LDS tile sort ->
// coalesced run writes), then aggregate entirely in LDS per bucket.
//
//   dinv[i] = rsqrt(deg_in[i]+1)
//   layer out[c] = dinv[c] * ( g[c] + sum_{col[e]==c} g[row[e]] ) + b
//   g[i] = (h[i] @ W) * dinv[i]
//
// ws (floats/u32): xe[n] dinv[n] g[16n] g2[n] gcnt[NB*16] gstart[NB*16]
//                  gcursor[NB*16] ebuf[ne]   (~33 MB)
// ebuf pack: (c_local<<24) | row   (row < 2^17, c_local < 256)

#define D_FEAT 128
#define HIDDEN 16
#define TILE 8192

__global__ __launch_bounds__(256) void k_init(float* xe, unsigned* gcnt, int n, int nb16) {
    int t = blockIdx.x * 256 + threadIdx.x;
    if (t < n) xe[t] = 0.f;
    if (t < nb16) gcnt[t] = 0u;
}

// xe[row[e]] += ea[e], rows sorted -> wave segmented scan, tail-lane atomic.
__global__ __launch_bounds__(256) void k_edge_prep(const int* __restrict__ row,
                                                   const float* __restrict__ ea,
                                                   float* xe, int ne) {
    int e = blockIdx.x * 256 + threadIdx.x;
    int lane = threadIdx.x & 63;
    bool valid = e < ne;
    int r = valid ? row[e] : -1;
    float a = valid ? ea[e] : 0.f;
    #pragma unroll
    for (int d = 1; d < 64; d <<= 1) {
        float up = __shfl_up(a, d);
        int  rup = __shfl_up(r, d);
        if (lane >= d && rup == r) a += up;
    }
    int rdn = __shfl_down(r, 1);
    bool tail = (lane == 63) || (rdn != r);
    if (valid && tail) unsafeAtomicAdd(&xe[r], a);
}

// Global bucket histogram (LDS-aggregated; padded counters: stride 16 u32/64B).
__global__ __launch_bounds__(256) void k_hist(const int* __restrict__ col,
                                              unsigned* gcnt, int ne, int nb) {
    __shared__ unsigned h[512];
    int tid = threadIdx.x;
    h[tid] = 0u; h[tid + 256] = 0u;
    __syncthreads();
    int tile0 = blockIdx.x * TILE;
    #pragma unroll 4
    for (int k = 0; k < 32; ++k) {
        int e = tile0 + tid + k * 256;
        if (e < ne) atomicAdd(&h[col[e] >> 8], 1u);
    }
    __syncthreads();
    for (int b = tid; b < nb; b += 256)
        if (h[b]) atomicAdd(&gcnt[b * 16], h[b]);
}

// Exclusive scan of bucket counts -> gstart, gcursor (single block).
__global__ __launch_bounds__(512) void k_scan(const unsigned* gcnt, unsigned* gstart,
                                              unsigned* gcursor, int nb) {
    __shared__ unsigned sc[512], hh[512];
    int tid = threadIdx.x;
    unsigned v = (tid < nb) ? gcnt[tid * 16] : 0u;
    hh[tid] = v; sc[tid] = v;
    __syncthreads();
    for (int off = 1; off < 512; off <<= 1) {
        unsigned u = (tid >= off) ? sc[tid - off] : 0u;
        __syncthreads();
        sc[tid] += u;
        __syncthreads();
    }
    if (tid < nb) {
        unsigned ex = sc[tid] - hh[tid];
        gstart[tid * 16] = ex;
        gcursor[tid * 16] = ex;
    }
}

// Tile counting sort: stage 8192 edges bucket-ordered in LDS, claim per-bucket
// global regions, write out as coalesced runs.
__global__ __launch_bounds__(512) void k_place(const int* __restrict__ row,
                                               const int* __restrict__ col,
                                               unsigned* gcursor, unsigned* ebuf,
                                               int ne, int nb) {
    __shared__ unsigned stage[TILE];
    __shared__ unsigned short sbuck[TILE];
    __shared__ unsigned h[512], sc[512], base_[512], cursor[512], gb[512];
    int tid = threadIdx.x;
    int tile0 = blockIdx.x * TILE;
    int cnt_t = min(TILE, ne - tile0);
    h[tid] = 0u;
    __syncthreads();
    int rr[16], cc[16];
    #pragma unroll
    for (int k = 0; k < 16; ++k) {
        int e = tile0 + tid + k * 512;
        if (e < ne) {
            rr[k] = row[e]; cc[k] = col[e];
            atomicAdd(&h[cc[k] >> 8], 1u);
        } else rr[k] = -1;
    }
    __syncthreads();
    sc[tid] = h[tid];
    __syncthreads();
    for (int off = 1; off < 512; off <<= 1) {
        unsigned u = (tid >= off) ? sc[tid - off] : 0u;
        __syncthreads();
        sc[tid] += u;
        __syncthreads();
    }
    unsigned ex = sc[tid] - h[tid];
    base_[tid] = ex;
    cursor[tid] = ex;
    if (tid < nb && h[tid]) gb[tid] = atomicAdd(&gcursor[tid * 16], h[tid]);
    __syncthreads();
    #pragma unroll
    for (int k = 0; k < 16; ++k) {
        if (rr[k] >= 0) {
            int b = cc[k] >> 8;
            unsigned p = atomicAdd(&cursor[b], 1u);
            stage[p] = (((unsigned)(cc[k] & 255)) << 24) | (unsigned)rr[k];
            sbuck[p] = (unsigned short)b;
        }
    }
    __syncthreads();
    for (int t = tid; t < cnt_t; t += 512) {
        int b = sbuck[t];
        ebuf[gb[b] + ((unsigned)t - base_[b])] = stage[t];
    }
}

// Per-bucket in-degree -> dinv.
__global__ __launch_bounds__(256) void k_deg_dinv(const unsigned* __restrict__ ebuf,
                                                  const unsigned* gcnt, const unsigned* gstart,
                                                  float* dinv, int n) {
    __shared__ unsigned dg[256];
    int b = blockIdx.x, tid = threadIdx.x;
    dg[tid] = 0u;
    __syncthreads();
    unsigned m = gcnt[b * 16], base = gstart[b * 16];
    for (unsigned i = tid; i < m; i += 256) atomicAdd(&dg[ebuf[base + i] >> 24], 1u);
    __syncthreads();
    int node = b * 256 + tid;
    if (node < n) dinv[node] = rsqrtf((float)dg[tid] + 1.0f);
}

// g[i][j] = (sum_k x[i][k]*W1[k][j] + xe[i]*W1[128][j]) * dinv[i]
__global__ __launch_bounds__(256) void k_gemm1(const float* __restrict__ x,
                                               const float* __restrict__ xe,
                                               const float* __restrict__ dinv,
                                               const float* __restrict__ W1,
                                               float* __restrict__ g, int n) {
    __shared__ float Ws[129 * 16];
    __shared__ float xs[64 * 132];
    int tid = threadIdx.x;
    for (int idx = tid; idx < 129 * 16; idx += 256) Ws[idx] = W1[idx];
    int n0 = blockIdx.x * 64;
    const float4* x4 = (const float4*)x;
    for (int idx = tid; idx < 64 * 32; idx += 256) {
        int r = idx >> 5, c = idx & 31;
        float4 v = (n0 + r < n) ? x4[(size_t)(n0 + r) * 32 + c]
                                : make_float4(0.f, 0.f, 0.f, 0.f);
        *(float4*)&xs[r * 132 + c * 4] = v;
    }
    if (tid < 64) {
        int r = tid;
        xs[r * 132 + 128] = (n0 + r < n) ? xe[n0 + r] : 0.f;
    }
    __syncthreads();
    int j  = tid & 15;
    int nb = tid >> 4;
    for (int rep = 0; rep < 4; ++rep) {
        int nl = nb + (rep << 4);
        int node = n0 + nl;
        const float* xrow = &xs[nl * 132];
        float acc = 0.f;
        #pragma unroll
        for (int k = 0; k < 128; k += 4) {
            float4 xv = *(const float4*)&xrow[k];
            acc += xv.x * Ws[(k + 0) * 16 + j];
            acc += xv.y * Ws[(k + 1) * 16 + j];
            acc += xv.z * Ws[(k + 2) * 16 + j];
            acc += xv.w * Ws[(k + 3) * 16 + j];
        }
        acc += xrow[128] * Ws[128 * 16 + j];
        if (node < n) g[node * 16 + j] = acc * dinv[node];
    }
}

// Layer-1 aggregation in LDS + fused epilogue (relu, @W2, *dinv) -> g2.
__global__ __launch_bounds__(256) void k_agg16b(const unsigned* __restrict__ ebuf,
                                                const unsigned* gcnt, const unsigned* gstart,
                                                const float* __restrict__ g,
                                                const float* __restrict__ dinv,
                                                const float* __restrict__ b1,
                                                const float* __restrict__ W2,
                                                float* __restrict__ g2, int n) {
    __shared__ float acc[256 * 16];
    int b = blockIdx.x, tid = threadIdx.x;
    #pragma unroll
    for (int k = 0; k < 16; ++k) acc[tid + k * 256] = 0.f;
    __syncthreads();
    unsigned m = gcnt[b * 16], base = gstart[b * 16];
    int j = tid & 15;
    long long mt = (long long)m * 16;
    for (long long i = tid; i < mt; i += 256) {
        unsigned e = (unsigned)(i >> 4);
        unsigned pk = ebuf[base + e];     // 16 lanes same addr -> broadcast
        unsigned r = pk & 0xFFFFFFu;
        unsigned cl = pk >> 24;
        unsafeAtomicAdd(&acc[cl * 16 + j], g[(size_t)r * 16 + j]);
    }
    __syncthreads();
    #pragma unroll
    for (int k = 0; k < 16; ++k) {
        int t = tid + k * 256;
        int node = b * 256 + (t >> 4);
        float p = 0.f;
        float di = 0.f;
        if (node < n) {
            di = dinv[node];
            float v = di * (g[(size_t)node * 16 + j] + acc[t]) + b1[j];
            v = fmaxf(v, 0.f);
            p = v * W2[j];
        }
        p += __shfl_down(p, 8, 16);
        p += __shfl_down(p, 4, 16);
        p += __shfl_down(p, 2, 16);
        p += __shfl_down(p, 1, 16);
        if (j == 0 && node < n) g2[node] = p * di;
    }
}

// Layer-2 aggregation in LDS + output.
__global__ __launch_bounds__(256) void k_agg1b(const unsigned* __restrict__ ebuf,
                                               const unsigned* gcnt, const unsigned* gstart,
                                               const float* __restrict__ g2,
                                               const float* __restrict__ dinv,
                                               const float* __restrict__ b2,
                                               float* __restrict__ out, int n) {
    __shared__ float a2[256];
    int b = blockIdx.x, tid = threadIdx.x;
    a2[tid] = 0.f;
    __syncthreads();
    unsigned m = gcnt[b * 16], base = gstart[b * 16];
    for (unsigned i = tid; i < m; i += 256) {
        unsigned pk = ebuf[base + i];
        unsafeAtomicAdd(&a2[pk >> 24], g2[pk & 0xFFFFFFu]);
    }
    __syncthreads();
    int node = b * 256 + tid;
    if (node < n) out[node] = dinv[node] * (g2[node] + a2[tid]) + b2[0];
}

extern "C" void kernel_launch(void* const* d_in, const int* in_sizes, int n_in,
                              void* d_out, int out_size, void* d_ws, size_t ws_size,
                              hipStream_t stream) {
    const float* x   = (const float*)d_in[0];
    const float* ea  = (const float*)d_in[1];
    const int*   row = (const int*)d_in[2];
    const int*   col = (const int*)d_in[3];
    const float* W1  = (const float*)d_in[4];
    const float* b1  = (const float*)d_in[5];
    const float* W2  = (const float*)d_in[6];
    const float* b2  = (const float*)d_in[7];
    float* out = (float*)d_out;

    int n  = in_sizes[0] / D_FEAT;   // 100000
    int ne = in_sizes[2];            // 6400000
    int nb = (n + 255) >> 8;         // 391 buckets of 256 nodes

    float* ws   = (float*)d_ws;
    float* xe   = ws;                      // n
    float* dinv = ws + (size_t)n;          // n
    float* g    = ws + (size_t)2 * n;      // 16n
    float* g2   = ws + (size_t)18 * n;     // n
    unsigned* gcnt    = (unsigned*)(ws + (size_t)19 * n);  // nb*16 (padded)
    unsigned* gstart  = gcnt + (size_t)nb * 16;
    unsigned* gcursor = gstart + (size_t)nb * 16;
    unsigned* ebuf    = gcursor + (size_t)nb * 16;         // ne

    dim3 blk(256);
    int g_init = (((n > nb * 16) ? n : nb * 16) + 255) / 256;
    int g_edge = (ne + 255) / 256;
    int g_tile = (ne + TILE - 1) / TILE;
    int g_gemm = (n + 63) / 64;

    k_init<<<g_init, blk, 0, stream>>>(xe, gcnt, n, nb * 16);
    k_edge_prep<<<g_edge, blk, 0, stream>>>(row, ea, xe, ne);
    k_hist<<<g_tile, blk, 0, stream>>>(col, gcnt, ne, nb);
    k_scan<<<1, 512, 0, stream>>>(gcnt, gstart, gcursor, nb);
    k_place<<<g_tile, 512, 0, stream>>>(row, col, gcursor, ebuf, ne, nb);
    k_deg_dinv<<<nb, blk, 0, stream>>>(ebuf, gcnt, gstart, dinv, n);
    k_gemm1<<<g_gemm, blk, 0, stream>>>(x, xe, dinv, W1, g, n);
    k_agg16b<<<nb, blk, 0, stream>>>(ebuf, gcnt, gstart, g, dinv, b1, W2, g2, n);
    k_agg1b<<<nb, blk, 0, stream>>>(ebuf, gcnt, gstart, g2, dinv, b2, out, n);
}

// Round 4
// 908.105 us; speedup vs baseline: 1.8349x; 1.1228x over previous
//
#include <hip/hip_runtime.h>

// GCN_88734024335852 — 2-layer GCN on MI355X
//
// R4: R3's bucket-LDS agg was latency-bound (391 blocks, 13% occupancy,
// HBM 1%, VALU 3%). Chunk each bucket x4 -> 1564 blocks, unroll gathers x4,
// flush LDS partials to per-chunk buffers (coalesced stores, no global
// atomics), reduce partials in the fused epilogue.
//
//   dinv[i] = rsqrt(deg_in[i]+1)
//   layer out[c] = dinv[c] * ( g[c] + sum_{col[e]==c} g[row[e]] ) + b
//   g[i] = (h[i] @ W) * dinv[i]
//
// ws (floats/u32): xe[n] dinv[n] g[16n] g2[n] gcnt/gstart/gcursor[nb*16]
//                  ebuf[ne] pacc[4*nb*4096] pacc2[4*nb*256]   (~62 MB)

#define D_FEAT 128
#define HIDDEN 16
#define TILE 8192
#define NCH 4

__global__ __launch_bounds__(256) void k_init(float* xe, unsigned* gcnt, int n, int nb16) {
    int t = blockIdx.x * 256 + threadIdx.x;
    if (t < n) xe[t] = 0.f;
    if (t < nb16) gcnt[t] = 0u;
}

// xe[row[e]] += ea[e], rows sorted -> wave segmented scan, tail-lane atomic.
__global__ __launch_bounds__(256) void k_edge_prep(const int* __restrict__ row,
                                                   const float* __restrict__ ea,
                                                   float* xe, int ne) {
    int e = blockIdx.x * 256 + threadIdx.x;
    int lane = threadIdx.x & 63;
    bool valid = e < ne;
    int r = valid ? row[e] : -1;
    float a = valid ? ea[e] : 0.f;
    #pragma unroll
    for (int d = 1; d < 64; d <<= 1) {
        float up = __shfl_up(a, d);
        int  rup = __shfl_up(r, d);
        if (lane >= d && rup == r) a += up;
    }
    int rdn = __shfl_down(r, 1);
    bool tail = (lane == 63) || (rdn != r);
    if (valid && tail) unsafeAtomicAdd(&xe[r], a);
}

// Global bucket histogram (LDS-aggregated).
__global__ __launch_bounds__(256) void k_hist(const int* __restrict__ col,
                                              unsigned* gcnt, int ne, int nb) {
    __shared__ unsigned h[512];
    int tid = threadIdx.x;
    h[tid] = 0u; h[tid + 256] = 0u;
    __syncthreads();
    int tile0 = blockIdx.x * TILE;
    #pragma unroll 4
    for (int k = 0; k < 32; ++k) {
        int e = tile0 + tid + k * 256;
        if (e < ne) atomicAdd(&h[col[e] >> 8], 1u);
    }
    __syncthreads();
    for (int b = tid; b < nb; b += 256)
        if (h[b]) atomicAdd(&gcnt[b * 16], h[b]);
}

// Exclusive scan of bucket counts (single block).
__global__ __launch_bounds__(512) void k_scan(const unsigned* gcnt, unsigned* gstart,
                                              unsigned* gcursor, int nb) {
    __shared__ unsigned sc[512], hh[512];
    int tid = threadIdx.x;
    unsigned v = (tid < nb) ? gcnt[tid * 16] : 0u;
    hh[tid] = v; sc[tid] = v;
    __syncthreads();
    for (int off = 1; off < 512; off <<= 1) {
        unsigned u = (tid >= off) ? sc[tid - off] : 0u;
        __syncthreads();
        sc[tid] += u;
        __syncthreads();
    }
    if (tid < nb) {
        unsigned ex = sc[tid] - hh[tid];
        gstart[tid * 16] = ex;
        gcursor[tid * 16] = ex;
    }
}

// Tile counting sort: stage bucket-ordered in LDS, coalesced run writes.
__global__ __launch_bounds__(512) void k_place(const int* __restrict__ row,
                                               const int* __restrict__ col,
                                               unsigned* gcursor, unsigned* ebuf,
                                               int ne, int nb) {
    __shared__ unsigned stage[TILE];
    __shared__ unsigned short sbuck[TILE];
    __shared__ unsigned h[512], sc[512], base_[512], cursor[512], gb[512];
    int tid = threadIdx.x;
    int tile0 = blockIdx.x * TILE;
    int cnt_t = min(TILE, ne - tile0);
    h[tid] = 0u;
    __syncthreads();
    int rr[16], cc[16];
    #pragma unroll
    for (int k = 0; k < 16; ++k) {
        int e = tile0 + tid + k * 512;
        if (e < ne) {
            rr[k] = row[e]; cc[k] = col[e];
            atomicAdd(&h[cc[k] >> 8], 1u);
        } else rr[k] = -1;
    }
    __syncthreads();
    sc[tid] = h[tid];
    __syncthreads();
    for (int off = 1; off < 512; off <<= 1) {
        unsigned u = (tid >= off) ? sc[tid - off] : 0u;
        __syncthreads();
        sc[tid] += u;
        __syncthreads();
    }
    unsigned ex = sc[tid] - h[tid];
    base_[tid] = ex;
    cursor[tid] = ex;
    if (tid < nb && h[tid]) gb[tid] = atomicAdd(&gcursor[tid * 16], h[tid]);
    __syncthreads();
    #pragma unroll
    for (int k = 0; k < 16; ++k) {
        if (rr[k] >= 0) {
            int b = cc[k] >> 8;
            unsigned p = atomicAdd(&cursor[b], 1u);
            stage[p] = (((unsigned)(cc[k] & 255)) << 24) | (unsigned)rr[k];
            sbuck[p] = (unsigned short)b;
        }
    }
    __syncthreads();
    for (int t = tid; t < cnt_t; t += 512) {
        int b = sbuck[t];
        ebuf[gb[b] + ((unsigned)t - base_[b])] = stage[t];
    }
}

// Per-bucket in-degree -> dinv.
__global__ __launch_bounds__(256) void k_deg_dinv(const unsigned* __restrict__ ebuf,
                                                  const unsigned* gcnt, const unsigned* gstart,
                                                  float* dinv, int n) {
    __shared__ unsigned dg[256];
    int b = blockIdx.x, tid = threadIdx.x;
    dg[tid] = 0u;
    __syncthreads();
    unsigned m = gcnt[b * 16], base = gstart[b * 16];
    for (unsigned i = tid; i < m; i += 256) atomicAdd(&dg[ebuf[base + i] >> 24], 1u);
    __syncthreads();
    int node = b * 256 + tid;
    if (node < n) dinv[node] = rsqrtf((float)dg[tid] + 1.0f);
}

// g[i][j] = (sum_k x[i][k]*W1[k][j] + xe[i]*W1[128][j]) * dinv[i]
__global__ __launch_bounds__(256) void k_gemm1(const float* __restrict__ x,
                                               const float* __restrict__ xe,
                                               const float* __restrict__ dinv,
                                               const float* __restrict__ W1,
                                               float* __restrict__ g, int n) {
    __shared__ float Ws[129 * 16];
    __shared__ float xs[64 * 132];
    int tid = threadIdx.x;
    for (int idx = tid; idx < 129 * 16; idx += 256) Ws[idx] = W1[idx];
    int n0 = blockIdx.x * 64;
    const float4* x4 = (const float4*)x;
    for (int idx = tid; idx < 64 * 32; idx += 256) {
        int r = idx >> 5, c = idx & 31;
        float4 v = (n0 + r < n) ? x4[(size_t)(n0 + r) * 32 + c]
                                : make_float4(0.f, 0.f, 0.f, 0.f);
        *(float4*)&xs[r * 132 + c * 4] = v;
    }
    if (tid < 64) {
        int r = tid;
        xs[r * 132 + 128] = (n0 + r < n) ? xe[n0 + r] : 0.f;
    }
    __syncthreads();
    int j  = tid & 15;
    int nb = tid >> 4;
    for (int rep = 0; rep < 4; ++rep) {
        int nl = nb + (rep << 4);
        int node = n0 + nl;
        const float* xrow = &xs[nl * 132];
        float acc = 0.f;
        #pragma unroll
        for (int k = 0; k < 128; k += 4) {
            float4 xv = *(const float4*)&xrow[k];
            acc += xv.x * Ws[(k + 0) * 16 + j];
            acc += xv.y * Ws[(k + 1) * 16 + j];
            acc += xv.z * Ws[(k + 2) * 16 + j];
            acc += xv.w * Ws[(k + 3) * 16 + j];
        }
        acc += xrow[128] * Ws[128 * 16 + j];
        if (node < n) g[node * 16 + j] = acc * dinv[node];
    }
}

// Layer-1 aggregation, chunked: block (b, ch) accumulates its slice of bucket b
// in LDS, streams partial to pacc (coalesced, non-atomic).
__global__ __launch_bounds__(256) void k_agg16c(const unsigned* __restrict__ ebuf,
                                                const unsigned* gcnt, const unsigned* gstart,
                                                const float* __restrict__ g,
                                                float* __restrict__ pacc, int nb) {
    __shared__ float acc[256 * 16];
    int b = blockIdx.x, ch = blockIdx.y, tid = threadIdx.x;
    #pragma unroll
    for (int k = 0; k < 16; ++k) acc[tid + k * 256] = 0.f;
    __syncthreads();
    unsigned m = gcnt[b * 16], base = gstart[b * 16];
    unsigned e0 = (unsigned)(((unsigned long long)m * ch) / NCH);
    unsigned e1 = (unsigned)(((unsigned long long)m * (ch + 1)) / NCH);
    int j = tid & 15;
    long long i   = (long long)e0 * 16 + tid;
    long long end = (long long)e1 * 16;
    for (; i + 768 < end; i += 1024) {
        unsigned pk0 = ebuf[base + (unsigned)((i      ) >> 4)];
        unsigned pk1 = ebuf[base + (unsigned)((i + 256) >> 4)];
        unsigned pk2 = ebuf[base + (unsigned)((i + 512) >> 4)];
        unsigned pk3 = ebuf[base + (unsigned)((i + 768) >> 4)];
        float v0 = g[(size_t)(pk0 & 0xFFFFFFu) * 16 + j];
        float v1 = g[(size_t)(pk1 & 0xFFFFFFu) * 16 + j];
        float v2 = g[(size_t)(pk2 & 0xFFFFFFu) * 16 + j];
        float v3 = g[(size_t)(pk3 & 0xFFFFFFu) * 16 + j];
        unsafeAtomicAdd(&acc[(pk0 >> 24) * 16 + j], v0);
        unsafeAtomicAdd(&acc[(pk1 >> 24) * 16 + j], v1);
        unsafeAtomicAdd(&acc[(pk2 >> 24) * 16 + j], v2);
        unsafeAtomicAdd(&acc[(pk3 >> 24) * 16 + j], v3);
    }
    for (; i < end; i += 256) {
        unsigned pk = ebuf[base + (unsigned)(i >> 4)];
        unsafeAtomicAdd(&acc[(pk >> 24) * 16 + j], g[(size_t)(pk & 0xFFFFFFu) * 16 + j]);
    }
    __syncthreads();
    float* dst = pacc + ((size_t)ch * nb + b) * 4096;
    #pragma unroll
    for (int k = 0; k < 16; ++k) dst[tid + k * 256] = acc[tid + k * 256];
}

// Fused: sum partials, epilogue (dinv, +b1, relu, @W2, *dinv) -> g2.
__global__ __launch_bounds__(256) void k_layer1_post(const float* __restrict__ pacc,
                                                     const float* __restrict__ g,
                                                     const float* __restrict__ dinv,
                                                     const float* __restrict__ b1,
                                                     const float* __restrict__ W2,
                                                     float* __restrict__ g2, int n, int nb) {
    int t = blockIdx.x * 256 + threadIdx.x;
    int i = t >> 4, j = t & 15;
    if (i >= n) return;
    int b = i >> 8;
    int off = ((i & 255) << 4) | j;
    float s = 0.f;
    #pragma unroll
    for (int ch = 0; ch < NCH; ++ch)
        s += pacc[((size_t)ch * nb + b) * 4096 + off];
    float di = dinv[i];
    float v = di * (g[(size_t)i * 16 + j] + s) + b1[j];
    v = fmaxf(v, 0.f);
    float p = v * W2[j];
    p += __shfl_down(p, 8, 16);
    p += __shfl_down(p, 4, 16);
    p += __shfl_down(p, 2, 16);
    p += __shfl_down(p, 1, 16);
    if (j == 0) g2[i] = p * di;
}

// Layer-2 aggregation, chunked.
__global__ __launch_bounds__(256) void k_agg1c(const unsigned* __restrict__ ebuf,
                                               const unsigned* gcnt, const unsigned* gstart,
                                               const float* __restrict__ g2,
                                               float* __restrict__ pacc2, int nb) {
    __shared__ float a2[256];
    int b = blockIdx.x, ch = blockIdx.y, tid = threadIdx.x;
    a2[tid] = 0.f;
    __syncthreads();
    unsigned m = gcnt[b * 16], base = gstart[b * 16];
    unsigned e0 = (unsigned)(((unsigned long long)m * ch) / NCH);
    unsigned e1 = (unsigned)(((unsigned long long)m * (ch + 1)) / NCH);
    unsigned i = e0 + tid;
    for (; i + 768 < e1; i += 1024) {
        unsigned pk0 = ebuf[base + i];
        unsigned pk1 = ebuf[base + i + 256];
        unsigned pk2 = ebuf[base + i + 512];
        unsigned pk3 = ebuf[base + i + 768];
        float v0 = g2[pk0 & 0xFFFFFFu];
        float v1 = g2[pk1 & 0xFFFFFFu];
        float v2 = g2[pk2 & 0xFFFFFFu];
        float v3 = g2[pk3 & 0xFFFFFFu];
        unsafeAtomicAdd(&a2[pk0 >> 24], v0);
        unsafeAtomicAdd(&a2[pk1 >> 24], v1);
        unsafeAtomicAdd(&a2[pk2 >> 24], v2);
        unsafeAtomicAdd(&a2[pk3 >> 24], v3);
    }
    for (; i < e1; i += 256) {
        unsigned pk = ebuf[base + i];
        unsafeAtomicAdd(&a2[pk >> 24], g2[pk & 0xFFFFFFu]);
    }
    __syncthreads();
    pacc2[((size_t)ch * nb + b) * 256 + tid] = a2[tid];
}

__global__ __launch_bounds__(256) void k_out(const float* __restrict__ pacc2,
                                             const float* __restrict__ dinv,
                                             const float* __restrict__ g2,
                                             const float* __restrict__ b2,
                                             float* __restrict__ out, int n, int nb) {
    int i = blockIdx.x * 256 + threadIdx.x;
    if (i >= n) return;
    int b = i >> 8, off = i & 255;
    float s = 0.f;
    #pragma unroll
    for (int ch = 0; ch < NCH; ++ch)
        s += pacc2[((size_t)ch * nb + b) * 256 + off];
    out[i] = dinv[i] * (g2[i] + s) + b2[0];
}

extern "C" void kernel_launch(void* const* d_in, const int* in_sizes, int n_in,
                              void* d_out, int out_size, void* d_ws, size_t ws_size,
                              hipStream_t stream) {
    const float* x   = (const float*)d_in[0];
    const float* ea  = (const float*)d_in[1];
    const int*   row = (const int*)d_in[2];
    const int*   col = (const int*)d_in[3];
    const float* W1  = (const float*)d_in[4];
    const float* b1  = (const float*)d_in[5];
    const float* W2  = (const float*)d_in[6];
    const float* b2  = (const float*)d_in[7];
    float* out = (float*)d_out;

    int n  = in_sizes[0] / D_FEAT;   // 100000
    int ne = in_sizes[2];            // 6400000
    int nb = (n + 255) >> 8;         // 391 buckets of 256 nodes

    float* ws   = (float*)d_ws;
    float* xe   = ws;                      // n
    float* dinv = ws + (size_t)n;          // n
    float* g    = ws + (size_t)2 * n;      // 16n
    float* g2   = ws + (size_t)18 * n;     // n
    unsigned* gcnt    = (unsigned*)(ws + (size_t)19 * n);  // nb*16
    unsigned* gstart  = gcnt + (size_t)nb * 16;
    unsigned* gcursor = gstart + (size_t)nb * 16;
    unsigned* ebuf    = gcursor + (size_t)nb * 16;         // ne
    float* pacc  = (float*)(ebuf + (size_t)ne);            // NCH*nb*4096
    float* pacc2 = pacc + (size_t)NCH * nb * 4096;         // NCH*nb*256

    dim3 blk(256);
    int g_init = (((n > nb * 16) ? n : nb * 16) + 255) / 256;
    int g_edge = (ne + 255) / 256;
    int g_tile = (ne + TILE - 1) / TILE;
    int g_gemm = (n + 63) / 64;
    int g_n16  = (n * HIDDEN + 255) / 256;
    int g_node = (n + 255) / 256;

    k_init<<<g_init, blk, 0, stream>>>(xe, gcnt, n, nb * 16);
    k_edge_prep<<<g_edge, blk, 0, stream>>>(row, ea, xe, ne);
    k_hist<<<g_tile, blk, 0, stream>>>(col, gcnt, ne, nb);
    k_scan<<<1, 512, 0, stream>>>(gcnt, gstart, gcursor, nb);
    k_place<<<g_tile, 512, 0, stream>>>(row, col, gcursor, ebuf, ne, nb);
    k_deg_dinv<<<nb, blk, 0, stream>>>(ebuf, gcnt, gstart, dinv, n);
    k_gemm1<<<g_gemm, blk, 0, stream>>>(x, xe, dinv, W1, g, n);
    k_agg16c<<<dim3(nb, NCH), blk, 0, stream>>>(ebuf, gcnt, gstart, g, pacc, nb);
    k_layer1_post<<<g_n16, blk, 0, stream>>>(pacc, g, dinv, b1, W2, g2, n, nb);
    k_agg1c<<<dim3(nb, NCH), blk, 0, stream>>>(ebuf, gcnt, gstart, g2, pacc2, nb);
    k_out<<<g_node, blk, 0, stream>>>(pacc2, dinv, g2, b2, out, n, nb);
}

// Round 5
// 855.597 us; speedup vs baseline: 1.9475x; 1.0614x over previous
//
#include <hip/hip_runtime.h>

// GCN_88734024335852 — 2-layer GCN on MI355X
//
// R5: R4's agg was MLP-starved (VGPR=12, 4 cachelines/instr in flight,
// VALU 3.9%, HBM 1.5%). Restructure: float4 gathers (4 lanes/edge -> 16
// lines/instr), unroll x4, NCH=8 chunks, flush LDS slices with coalesced
// global atomics into acc1/acc2 (no partial buffers). Fused hist+edge_prep.
//
//   dinv[i] = rsqrt(deg_in[i]+1)
//   layer out[c] = dinv[c] * ( g[c] + sum_{col[e]==c} g[row[e]] ) + b
//   g[i] = (h[i] @ W) * dinv[i]
//
// ws: xe[n] dinv[n] g[16n] g2[n] acc1[16n] acc2[n] gcnt/gstart/gcursor[nb*16]
//     ebuf[ne]   (~40 MB)

#define D_FEAT 128
#define HIDDEN 16
#define TILE 8192
#define NCH 8

__global__ __launch_bounds__(256) void k_init(float* xe, float* acc1, float* acc2,
                                              unsigned* gcnt, int n, int nb16) {
    int t = blockIdx.x * 256 + threadIdx.x;
    if (t < 16 * n) acc1[t] = 0.f;
    if (t < n) { xe[t] = 0.f; acc2[t] = 0.f; }
    if (t < nb16) gcnt[t] = 0u;
}

// Fused: xe segment-sum (rows sorted -> wave scan) + bucket histogram.
__global__ __launch_bounds__(256) void k_prep(const int* __restrict__ row,
                                              const int* __restrict__ col,
                                              const float* __restrict__ ea,
                                              float* xe, unsigned* gcnt, int ne, int nb) {
    __shared__ unsigned h[512];
    int tid = threadIdx.x;
    h[tid] = 0u; h[tid + 256] = 0u;
    __syncthreads();
    int lane = tid & 63;
    int tile0 = blockIdx.x * TILE;
    for (int k = 0; k < TILE / 256; ++k) {
        int e = tile0 + k * 256 + tid;
        bool valid = e < ne;
        int r = valid ? row[e] : -1;
        float a = valid ? ea[e] : 0.f;
        if (valid) atomicAdd(&h[col[e] >> 8], 1u);
        #pragma unroll
        for (int d = 1; d < 64; d <<= 1) {
            float up = __shfl_up(a, d);
            int  rup = __shfl_up(r, d);
            if (lane >= d && rup == r) a += up;
        }
        int rdn = __shfl_down(r, 1);
        bool tail = (lane == 63) || (rdn != r);
        if (valid && tail) unsafeAtomicAdd(&xe[r], a);
    }
    __syncthreads();
    for (int b = tid; b < nb; b += 256)
        if (h[b]) atomicAdd(&gcnt[b * 16], h[b]);
}

// Exclusive scan of bucket counts (single block).
__global__ __launch_bounds__(512) void k_scan(const unsigned* gcnt, unsigned* gstart,
                                              unsigned* gcursor, int nb) {
    __shared__ unsigned sc[512], hh[512];
    int tid = threadIdx.x;
    unsigned v = (tid < nb) ? gcnt[tid * 16] : 0u;
    hh[tid] = v; sc[tid] = v;
    __syncthreads();
    for (int off = 1; off < 512; off <<= 1) {
        unsigned u = (tid >= off) ? sc[tid - off] : 0u;
        __syncthreads();
        sc[tid] += u;
        __syncthreads();
    }
    if (tid < nb) {
        unsigned ex = sc[tid] - hh[tid];
        gstart[tid * 16] = ex;
        gcursor[tid * 16] = ex;
    }
}

// Tile counting sort: stage bucket-ordered in LDS, coalesced run writes.
__global__ __launch_bounds__(512) void k_place(const int* __restrict__ row,
                                               const int* __restrict__ col,
                                               unsigned* gcursor, unsigned* ebuf,
                                               int ne, int nb) {
    __shared__ unsigned stage[TILE];
    __shared__ unsigned short sbuck[TILE];
    __shared__ unsigned h[512], sc[512], base_[512], cursor[512], gb[512];
    int tid = threadIdx.x;
    int tile0 = blockIdx.x * TILE;
    int cnt_t = min(TILE, ne - tile0);
    h[tid] = 0u;
    __syncthreads();
    int rr[16], cc[16];
    #pragma unroll
    for (int k = 0; k < 16; ++k) {
        int e = tile0 + tid + k * 512;
        if (e < ne) {
            rr[k] = row[e]; cc[k] = col[e];
            atomicAdd(&h[cc[k] >> 8], 1u);
        } else rr[k] = -1;
    }
    __syncthreads();
    sc[tid] = h[tid];
    __syncthreads();
    for (int off = 1; off < 512; off <<= 1) {
        unsigned u = (tid >= off) ? sc[tid - off] : 0u;
        __syncthreads();
        sc[tid] += u;
        __syncthreads();
    }
    unsigned ex = sc[tid] - h[tid];
    base_[tid] = ex;
    cursor[tid] = ex;
    if (tid < nb && h[tid]) gb[tid] = atomicAdd(&gcursor[tid * 16], h[tid]);
    __syncthreads();
    #pragma unroll
    for (int k = 0; k < 16; ++k) {
        if (rr[k] >= 0) {
            int b = cc[k] >> 8;
            unsigned p = atomicAdd(&cursor[b], 1u);
            stage[p] = (((unsigned)(cc[k] & 255)) << 24) | (unsigned)rr[k];
            sbuck[p] = (unsigned short)b;
        }
    }
    __syncthreads();
    for (int t = tid; t < cnt_t; t += 512) {
        int b = sbuck[t];
        ebuf[gb[b] + ((unsigned)t - base_[b])] = stage[t];
    }
}

// Per-bucket in-degree -> dinv.
__global__ __launch_bounds__(256) void k_deg_dinv(const unsigned* __restrict__ ebuf,
                                                  const unsigned* gcnt, const unsigned* gstart,
                                                  float* dinv, int n) {
    __shared__ unsigned dg[256];
    int b = blockIdx.x, tid = threadIdx.x;
    dg[tid] = 0u;
    __syncthreads();
    unsigned m = gcnt[b * 16], base = gstart[b * 16];
    for (unsigned i = tid; i < m; i += 256) atomicAdd(&dg[ebuf[base + i] >> 24], 1u);
    __syncthreads();
    int node = b * 256 + tid;
    if (node < n) dinv[node] = rsqrtf((float)dg[tid] + 1.0f);
}

// g[i][j] = (sum_k x[i][k]*W1[k][j] + xe[i]*W1[128][j]) * dinv[i]
__global__ __launch_bounds__(256) void k_gemm1(const float* __restrict__ x,
                                               const float* __restrict__ xe,
                                               const float* __restrict__ dinv,
                                               const float* __restrict__ W1,
                                               float* __restrict__ g, int n) {
    __shared__ float Ws[129 * 16];
    __shared__ float xs[64 * 132];
    int tid = threadIdx.x;
    for (int idx = tid; idx < 129 * 16; idx += 256) Ws[idx] = W1[idx];
    int n0 = blockIdx.x * 64;
    const float4* x4 = (const float4*)x;
    for (int idx = tid; idx < 64 * 32; idx += 256) {
        int r = idx >> 5, c = idx & 31;
        float4 v = (n0 + r < n) ? x4[(size_t)(n0 + r) * 32 + c]
                                : make_float4(0.f, 0.f, 0.f, 0.f);
        *(float4*)&xs[r * 132 + c * 4] = v;
    }
    if (tid < 64) {
        int r = tid;
        xs[r * 132 + 128] = (n0 + r < n) ? xe[n0 + r] : 0.f;
    }
    __syncthreads();
    int j  = tid & 15;
    int nb = tid >> 4;
    for (int rep = 0; rep < 4; ++rep) {
        int nl = nb + (rep << 4);
        int node = n0 + nl;
        const float* xrow = &xs[nl * 132];
        float acc = 0.f;
        #pragma unroll
        for (int k = 0; k < 128; k += 4) {
            float4 xv = *(const float4*)&xrow[k];
            acc += xv.x * Ws[(k + 0) * 16 + j];
            acc += xv.y * Ws[(k + 1) * 16 + j];
            acc += xv.z * Ws[(k + 2) * 16 + j];
            acc += xv.w * Ws[(k + 3) * 16 + j];
        }
        acc += xrow[128] * Ws[128 * 16 + j];
        if (node < n) g[node * 16 + j] = acc * dinv[node];
    }
}

// Layer-1 aggregation: block (b, ch); 4 lanes per edge, float4 gathers
// (16 distinct cachelines per wave load). Flush LDS slice with coalesced
// global atomics into acc1.
__global__ __launch_bounds__(256) void k_agg16d(const unsigned* __restrict__ ebuf,
                                                const unsigned* gcnt, const unsigned* gstart,
                                                const float* __restrict__ g,
                                                float* __restrict__ acc1, int nb) {
    __shared__ float acc[256 * 16];
    int b = blockIdx.x, ch = blockIdx.y, tid = threadIdx.x;
    #pragma unroll
    for (int k = 0; k < 16; ++k) acc[tid + k * 256] = 0.f;
    __syncthreads();
    unsigned m = gcnt[b * 16], base = gstart[b * 16];
    unsigned e0 = (unsigned)(((unsigned long long)m * ch) / NCH);
    unsigned e1 = (unsigned)(((unsigned long long)m * (ch + 1)) / NCH);
    const float4* g4 = (const float4*)g;
    int q = tid & 3;
    unsigned i = e0 + (tid >> 2);
    for (; i + 192 < e1; i += 256) {
        unsigned pk0 = ebuf[base + i];
        unsigned pk1 = ebuf[base + i + 64];
        unsigned pk2 = ebuf[base + i + 128];
        unsigned pk3 = ebuf[base + i + 192];
        float4 v0 = g4[(size_t)(pk0 & 0xFFFFFFu) * 4 + q];
        float4 v1 = g4[(size_t)(pk1 & 0xFFFFFFu) * 4 + q];
        float4 v2 = g4[(size_t)(pk2 & 0xFFFFFFu) * 4 + q];
        float4 v3 = g4[(size_t)(pk3 & 0xFFFFFFu) * 4 + q];
        float* a0 = &acc[(pk0 >> 24) * 16 + q * 4];
        float* a1 = &acc[(pk1 >> 24) * 16 + q * 4];
        float* a2 = &acc[(pk2 >> 24) * 16 + q * 4];
        float* a3 = &acc[(pk3 >> 24) * 16 + q * 4];
        unsafeAtomicAdd(a0 + 0, v0.x); unsafeAtomicAdd(a0 + 1, v0.y);
        unsafeAtomicAdd(a0 + 2, v0.z); unsafeAtomicAdd(a0 + 3, v0.w);
        unsafeAtomicAdd(a1 + 0, v1.x); unsafeAtomicAdd(a1 + 1, v1.y);
        unsafeAtomicAdd(a1 + 2, v1.z); unsafeAtomicAdd(a1 + 3, v1.w);
        unsafeAtomicAdd(a2 + 0, v2.x); unsafeAtomicAdd(a2 + 1, v2.y);
        unsafeAtomicAdd(a2 + 2, v2.z); unsafeAtomicAdd(a2 + 3, v2.w);
        unsafeAtomicAdd(a3 + 0, v3.x); unsafeAtomicAdd(a3 + 1, v3.y);
        unsafeAtomicAdd(a3 + 2, v3.z); unsafeAtomicAdd(a3 + 3, v3.w);
    }
    for (; i < e1; i += 64) {
        unsigned pk = ebuf[base + i];
        float4 v = g4[(size_t)(pk & 0xFFFFFFu) * 4 + q];
        float* a = &acc[(pk >> 24) * 16 + q * 4];
        unsafeAtomicAdd(a + 0, v.x); unsafeAtomicAdd(a + 1, v.y);
        unsafeAtomicAdd(a + 2, v.z); unsafeAtomicAdd(a + 3, v.w);
    }
    __syncthreads();
    float* dst = acc1 + (size_t)b * 4096;
    #pragma unroll
    for (int k = 0; k < 16; ++k) {
        float v = acc[tid + k * 256];
        if (v != 0.f) unsafeAtomicAdd(&dst[tid + k * 256], v);
    }
}

// Epilogue: h1 = relu(dinv*(g+acc1)+b1); g2 = (h1@W2)*dinv.
__global__ __launch_bounds__(256) void k_layer1_post(const float* __restrict__ acc1,
                                                     const float* __restrict__ g,
                                                     const float* __restrict__ dinv,
                                                     const float* __restrict__ b1,
                                                     const float* __restrict__ W2,
                                                     float* __restrict__ g2, int n) {
    int t = blockIdx.x * 256 + threadIdx.x;
    int i = t >> 4, j = t & 15;
    if (i >= n) return;
    float di = dinv[i];
    float v = di * (g[(size_t)i * 16 + j] + acc1[(size_t)i * 16 + j]) + b1[j];
    v = fmaxf(v, 0.f);
    float p = v * W2[j];
    p += __shfl_down(p, 8, 16);
    p += __shfl_down(p, 4, 16);
    p += __shfl_down(p, 2, 16);
    p += __shfl_down(p, 1, 16);
    if (j == 0) g2[i] = p * di;
}

// Layer-2 aggregation, chunked; flush coalesced atomics into acc2.
__global__ __launch_bounds__(256) void k_agg1d(const unsigned* __restrict__ ebuf,
                                               const unsigned* gcnt, const unsigned* gstart,
                                               const float* __restrict__ g2,
                                               float* __restrict__ acc2, int nb) {
    __shared__ float a2[256];
    int b = blockIdx.x, ch = blockIdx.y, tid = threadIdx.x;
    a2[tid] = 0.f;
    __syncthreads();
    unsigned m = gcnt[b * 16], base = gstart[b * 16];
    unsigned e0 = (unsigned)(((unsigned long long)m * ch) / NCH);
    unsigned e1 = (unsigned)(((unsigned long long)m * (ch + 1)) / NCH);
    unsigned i = e0 + tid;
    for (; i + 768 < e1; i += 1024) {
        unsigned pk0 = ebuf[base + i];
        unsigned pk1 = ebuf[base + i + 256];
        unsigned pk2 = ebuf[base + i + 512];
        unsigned pk3 = ebuf[base + i + 768];
        float v0 = g2[pk0 & 0xFFFFFFu];
        float v1 = g2[pk1 & 0xFFFFFFu];
        float v2 = g2[pk2 & 0xFFFFFFu];
        float v3 = g2[pk3 & 0xFFFFFFu];
        unsafeAtomicAdd(&a2[pk0 >> 24], v0);
        unsafeAtomicAdd(&a2[pk1 >> 24], v1);
        unsafeAtomicAdd(&a2[pk2 >> 24], v2);
        unsafeAtomicAdd(&a2[pk3 >> 24], v3);
    }
    for (; i < e1; i += 256) {
        unsigned pk = ebuf[base + i];
        unsafeAtomicAdd(&a2[pk >> 24], g2[pk & 0xFFFFFFu]);
    }
    __syncthreads();
    float v = a2[tid];
    if (v != 0.f) unsafeAtomicAdd(&acc2[b * 256 + tid], v);
}

__global__ __launch_bounds__(256) void k_out(const float* __restrict__ acc2,
                                             const float* __restrict__ dinv,
                                             const float* __restrict__ g2,
                                             const float* __restrict__ b2,
                                             float* __restrict__ out, int n) {
    int i = blockIdx.x * 256 + threadIdx.x;
    if (i >= n) return;
    out[i] = dinv[i] * (g2[i] + acc2[i]) + b2[0];
}

extern "C" void kernel_launch(void* const* d_in, const int* in_sizes, int n_in,
                              void* d_out, int out_size, void* d_ws, size_t ws_size,
                              hipStream_t stream) {
    const float* x   = (const float*)d_in[0];
    const float* ea  = (const float*)d_in[1];
    const int*   row = (const int*)d_in[2];
    const int*   col = (const int*)d_in[3];
    const float* W1  = (const float*)d_in[4];
    const float* b1  = (const float*)d_in[5];
    const float* W2  = (const float*)d_in[6];
    const float* b2  = (const float*)d_in[7];
    float* out = (float*)d_out;

    int n  = in_sizes[0] / D_FEAT;   // 100000
    int ne = in_sizes[2];            // 6400000
    int nb = (n + 255) >> 8;         // 391 buckets of 256 nodes

    float* ws   = (float*)d_ws;
    float* xe   = ws;                      // n
    float* dinv = ws + (size_t)n;          // n
    float* g    = ws + (size_t)2 * n;      // 16n
    float* g2   = ws + (size_t)18 * n;     // n
    float* acc1 = ws + (size_t)19 * n;     // 16n
    float* acc2 = ws + (size_t)35 * n;     // n
    unsigned* gcnt    = (unsigned*)(ws + (size_t)36 * n);  // nb*16
    unsigned* gstart  = gcnt + (size_t)nb * 16;
    unsigned* gcursor = gstart + (size_t)nb * 16;
    unsigned* ebuf    = gcursor + (size_t)nb * 16;         // ne

    dim3 blk(256);
    int g_init = (16 * n + 255) / 256;
    int g_tile = (ne + TILE - 1) / TILE;
    int g_gemm = (n + 63) / 64;
    int g_n16  = (n * HIDDEN + 255) / 256;
    int g_node = (n + 255) / 256;

    k_init<<<g_init, blk, 0, stream>>>(xe, acc1, acc2, gcnt, n, nb * 16);
    k_prep<<<g_tile, blk, 0, stream>>>(row, col, ea, xe, gcnt, ne, nb);
    k_scan<<<1, 512, 0, stream>>>(gcnt, gstart, gcursor, nb);
    k_place<<<g_tile, 512, 0, stream>>>(row, col, gcursor, ebuf, ne, nb);
    k_deg_dinv<<<nb, blk, 0, stream>>>(ebuf, gcnt, gstart, dinv, n);
    k_gemm1<<<g_gemm, blk, 0, stream>>>(x, xe, dinv, W1, g, n);
    k_agg16d<<<dim3(nb, NCH), blk, 0, stream>>>(ebuf, gcnt, gstart, g, acc1, nb);
    k_layer1_post<<<g_n16, blk, 0, stream>>>(acc1, g, dinv, b1, W2, g2, n);
    k_agg1d<<<dim3(nb, NCH), blk, 0, stream>>>(ebuf, gcnt, gstart, g2, acc2, nb);
    k_out<<<g_node, blk, 0, stream>>>(acc2, dinv, g2, b2, out, n);
}